// Round 1
// baseline (550.051 us; speedup 1.0000x reference)
//
#include <hip/hip_runtime.h>
#include <math.h>

#define HB 64      // batch
#define HD 1024    // hidden / input dim

// ---------------------------------------------------------------------------
// Tiled f32 GEMM-ish: out[b][mbase+mj] = act( dot(in[b,:K], W[m,:K]) + bias[m] )
// Block: 256 threads = 4 waves. Tile: 16 m-columns x all 64 batches.
// K chunked by 32; X chunk (64x32) and W chunk (16x32) staged in LDS.
// Thread t: b = t&63 (lane), mg = t>>6 (wave) owns 4 m's -> 4 accumulators.
// LDS reads: Xs[b][n] is 2-way bank aliasing (free on CDNA4); Ws wave-uniform
// (broadcast).
// ---------------------------------------------------------------------------
__device__ __forceinline__ void lin_tile(
    const float* __restrict__ in0, const float* __restrict__ in1,
    const float* __restrict__ W, const float* __restrict__ bias,
    float* __restrict__ out, int K, int act, int mbase)
{
    __shared__ float Xs[64][33];
    __shared__ float Ws[16][32];
    const int t  = threadIdx.x;
    const int b  = t & 63;
    const int mg = t >> 6;
    float acc[4] = {0.f, 0.f, 0.f, 0.f};

    for (int n0 = 0; n0 < K; n0 += 32) {
        // stage X chunk: 64 b x 32 n
        #pragma unroll
        for (int i = 0; i < 8; ++i) {
            int idx = t + 256 * i;
            int bb = idx >> 5, nn = idx & 31;
            int n = n0 + nn;
            Xs[bb][nn] = (n < HD) ? in0[bb * HD + n] : in1[bb * HD + (n - HD)];
        }
        // stage W chunk: 16 m x 32 n
        #pragma unroll
        for (int i = 0; i < 2; ++i) {
            int idx = t + 256 * i;
            int mm = idx >> 5, nn = idx & 31;
            Ws[mm][nn] = W[(long long)(mbase + mm) * K + n0 + nn];
        }
        __syncthreads();
        #pragma unroll
        for (int n = 0; n < 32; ++n) {
            float xv = Xs[b][n];
            acc[0] = fmaf(xv, Ws[mg * 4 + 0][n], acc[0]);
            acc[1] = fmaf(xv, Ws[mg * 4 + 1][n], acc[1]);
            acc[2] = fmaf(xv, Ws[mg * 4 + 2][n], acc[2]);
            acc[3] = fmaf(xv, Ws[mg * 4 + 3][n], acc[3]);
        }
        __syncthreads();
    }
    #pragma unroll
    for (int j = 0; j < 4; ++j) {
        int m = mbase + mg * 4 + j;
        float z = acc[j] + bias[m];
        if (act) z = 1.0f / (1.0f + expf(-z));
        out[b * HD + m] = z;
    }
}

// grid.y picks which of the 5 linears; grid.x tiles m (1024/16 = 64)
__global__ __launch_bounds__(256) void qkvfi_kernel(
    const float* __restrict__ x, const float* __restrict__ h,
    const float* __restrict__ Wq, const float* __restrict__ bq,
    const float* __restrict__ Wk, const float* __restrict__ bk,
    const float* __restrict__ Wv, const float* __restrict__ bv,
    const float* __restrict__ Wf, const float* __restrict__ bf,
    const float* __restrict__ Wi, const float* __restrict__ bi,
    float* __restrict__ q, float* __restrict__ k, float* __restrict__ v,
    float* __restrict__ fg, float* __restrict__ ig)
{
    const float* W; const float* bias; float* out; int K; int act;
    switch (blockIdx.y) {
        case 0:  W = Wq; bias = bq; out = q;  K = HD;     act = 0; break;
        case 1:  W = Wk; bias = bk; out = k;  K = HD;     act = 0; break;
        case 2:  W = Wv; bias = bv; out = v;  K = HD;     act = 0; break;
        case 3:  W = Wf; bias = bf; out = fg; K = 2 * HD; act = 1; break;
        default: W = Wi; bias = bi; out = ig; K = 2 * HD; act = 1; break;
    }
    lin_tile(x, h, W, bias, out, K, act, blockIdx.x * 16);
}

__global__ __launch_bounds__(256) void out_lin_kernel(
    const float* __restrict__ tin,
    const float* __restrict__ Wo, const float* __restrict__ bo,
    float* __restrict__ hnew)
{
    lin_tile(tin, tin, Wo, bo, hnew, HD, 0, blockIdx.x * 16);
}

// ---------------------------------------------------------------------------
// Fused C update + readout:
//   Cn[b,m,n] = f[b,m]*C[b,m,n] + (i[b,m]*k[b,m])*v[b,n]
//   tr[b,m]   = tanh( sum_n Cn[b,m,n] * q[b,n] )
// One wave per (b,m) row; 4 float4 per lane; wave shuffle-reduce for r.
// ---------------------------------------------------------------------------
__global__ __launch_bounds__(256) void update_kernel(
    const float* __restrict__ C,
    const float* __restrict__ q, const float* __restrict__ k,
    const float* __restrict__ v, const float* __restrict__ fg,
    const float* __restrict__ ig,
    float* __restrict__ Cn, float* __restrict__ tr)
{
    const int wid  = threadIdx.x >> 6;
    const int lane = threadIdx.x & 63;
    const int row  = blockIdx.x * 4 + wid;      // 0 .. B*HD-1
    const int b    = row >> 10;
    const int m    = row & (HD - 1);

    const float fm  = fg[b * HD + m];
    const float ikm = ig[b * HD + m] * k[b * HD + m];

    const float4* C4 = (const float4*)C;
    const float4* V4 = (const float4*)v;
    const float4* Q4 = (const float4*)q;
    float4*       N4 = (float4*)Cn;

    const int base  = row * (HD / 4);
    const int vbase = b * (HD / 4);

    float racc = 0.f;
    #pragma unroll
    for (int j = 0; j < 4; ++j) {
        int o = lane + 64 * j;
        float4 c4 = C4[base + o];
        float4 v4 = V4[vbase + o];
        float4 q4 = Q4[vbase + o];
        float4 cn;
        cn.x = fmaf(fm, c4.x, ikm * v4.x);
        cn.y = fmaf(fm, c4.y, ikm * v4.y);
        cn.z = fmaf(fm, c4.z, ikm * v4.z);
        cn.w = fmaf(fm, c4.w, ikm * v4.w);
        N4[base + o] = cn;
        racc += cn.x * q4.x + cn.y * q4.y + cn.z * q4.z + cn.w * q4.w;
    }
    #pragma unroll
    for (int off = 32; off; off >>= 1) racc += __shfl_xor(racc, off);
    if (lane == 0) tr[row] = tanhf(racc);
}

extern "C" void kernel_launch(void* const* d_in, const int* in_sizes, int n_in,
                              void* d_out, int out_size, void* d_ws, size_t ws_size,
                              hipStream_t stream) {
    const float* x  = (const float*)d_in[0];
    const float* h  = (const float*)d_in[1];
    const float* C  = (const float*)d_in[2];
    const float* Wq = (const float*)d_in[3];
    const float* bq = (const float*)d_in[4];
    const float* Wk = (const float*)d_in[5];
    const float* bk = (const float*)d_in[6];
    const float* Wv = (const float*)d_in[7];
    const float* bv = (const float*)d_in[8];
    const float* Wf = (const float*)d_in[9];
    const float* bf = (const float*)d_in[10];
    const float* Wi = (const float*)d_in[11];
    const float* bi = (const float*)d_in[12];
    const float* Wo = (const float*)d_in[13];
    const float* bo = (const float*)d_in[14];

    float* outp = (float*)d_out;
    float* hnew = outp;                    // [B,HD]   65536 floats
    float* Cn   = outp + HB * HD;          // [B,HD,HD]

    float* ws = (float*)d_ws;
    float* q  = ws + 0 * HB * HD;
    float* k  = ws + 1 * HB * HD;
    float* v  = ws + 2 * HB * HD;
    float* fg = ws + 3 * HB * HD;
    float* ig = ws + 4 * HB * HD;
    float* tr = ws + 5 * HB * HD;

    qkvfi_kernel<<<dim3(64, 5), 256, 0, stream>>>(
        x, h, Wq, bq, Wk, bk, Wv, bv, Wf, bf, Wi, bi, q, k, v, fg, ig);

    update_kernel<<<dim3((HB * HD) / 4), 256, 0, stream>>>(
        C, q, k, v, fg, ig, Cn, tr);

    out_lin_kernel<<<dim3(64), 256, 0, stream>>>(tr, Wo, bo, hnew);
}

// Round 3
// 128.708 us; speedup vs baseline: 4.2736x; 4.2736x over previous
//
#include <hip/hip_runtime.h>
#include <math.h>

#define HB 64      // batch
#define HD 1024    // hidden / input dim
#define KS 128     // K-slice per split-K block
#define XS 68      // padded LDS row stride (floats), mult of 4 for float4 reads

typedef float f32x4 __attribute__((ext_vector_type(4)));

// ---------------------------------------------------------------------------
// Split-K register-tiled GEMM slice:
//   P[b][m0+mj] = sum_{n=k0}^{k0+KS-1} X[b][n] * W[m][n]
// Block: 256 threads. Tile: 64 m x 64 b. Thread (bx=t&15, my=t>>4) owns a
// 4b x 4m register tile -> 16 FMA per (1 X float4 + 1 W float4) LDS read.
// LDS is transposed (Xs[n][b], Ws[n][m]) so fragment reads are ds_read_b128.
// ---------------------------------------------------------------------------
__device__ __forceinline__ void splitk_tile(
    const float* __restrict__ X0, int noff,      // element n read as X0[b*HD + n - noff]
    const float* __restrict__ W, int K,
    int m0, int k0,
    float* __restrict__ P)                       // 65536-float slab for this (gemm,split)
{
    __shared__ __align__(16) float Xs[32][XS];
    __shared__ __align__(16) float Ws[32][XS];
    const int t  = threadIdx.x;
    const int bx = t & 15;
    const int my = t >> 4;
    float acc[4][4] = {};

    for (int kc = 0; kc < KS; kc += 32) {
        const int n0 = k0 + kc;
        // stage X chunk: 64 b x 32 n (512 float4, 2 per thread), transposed
        #pragma unroll
        for (int i = 0; i < 2; ++i) {
            int u = t + 256 * i;
            int b = u >> 3, nq = u & 7;
            float4 xv = *(const float4*)&X0[b * HD + (n0 - noff) + nq * 4];
            Xs[nq * 4 + 0][b] = xv.x; Xs[nq * 4 + 1][b] = xv.y;
            Xs[nq * 4 + 2][b] = xv.z; Xs[nq * 4 + 3][b] = xv.w;
        }
        // stage W chunk: 64 m x 32 n, transposed
        #pragma unroll
        for (int i = 0; i < 2; ++i) {
            int u = t + 256 * i;
            int mm = u >> 3, nq = u & 7;
            float4 wv = *(const float4*)&W[(long long)(m0 + mm) * K + n0 + nq * 4];
            Ws[nq * 4 + 0][mm] = wv.x; Ws[nq * 4 + 1][mm] = wv.y;
            Ws[nq * 4 + 2][mm] = wv.z; Ws[nq * 4 + 3][mm] = wv.w;
        }
        __syncthreads();
        #pragma unroll
        for (int n = 0; n < 32; ++n) {
            float4 xv = *(const float4*)&Xs[n][bx * 4];
            float4 wv = *(const float4*)&Ws[n][my * 4];
            float xe[4] = {xv.x, xv.y, xv.z, xv.w};
            float we[4] = {wv.x, wv.y, wv.z, wv.w};
            #pragma unroll
            for (int i = 0; i < 4; ++i)
                #pragma unroll
                for (int j = 0; j < 4; ++j)
                    acc[i][j] = fmaf(xe[i], we[j], acc[i][j]);
        }
        __syncthreads();
    }
    #pragma unroll
    for (int i = 0; i < 4; ++i)
        #pragma unroll
        for (int j = 0; j < 4; ++j)
            P[(bx * 4 + i) * HD + m0 + my * 4 + j] = acc[i][j];
}

// grid.x = 16 m-tiles; grid.y = 56 (gemm,split) units:
//   gy 0..23  : q/k/v   (8 splits each, K=1024)
//   gy 24..55 : f/i     (16 splits each, K=2048)
__global__ __launch_bounds__(256) void qkvfi_splitk(
    const float* __restrict__ x, const float* __restrict__ h,
    const float* __restrict__ Wq, const float* __restrict__ Wk,
    const float* __restrict__ Wv, const float* __restrict__ Wf,
    const float* __restrict__ Wi, float* __restrict__ P)
{
    const int gy = blockIdx.y;
    const float* W; int K, split;
    if (gy < 24) {
        int g = gy >> 3; split = gy & 7; K = HD;
        W = (g == 0) ? Wq : (g == 1) ? Wk : Wv;
    } else {
        int tt = gy - 24; int g = tt >> 4; split = tt & 15; K = 2 * HD;
        W = g ? Wi : Wf;
    }
    const int k0 = split * KS;
    const float* X0; int noff;
    if (k0 < HD) { X0 = x; noff = 0; } else { X0 = h; noff = HD; }
    splitk_tile(X0, noff, W, K, blockIdx.x * 64, k0, P + (size_t)gy * (HB * HD));
}

__global__ __launch_bounds__(256) void out_splitk(
    const float* __restrict__ tr, const float* __restrict__ Wo,
    float* __restrict__ P2)
{
    const int split = blockIdx.y;   // 0..7
    splitk_tile(tr, 0, Wo, HD, blockIdx.x * 64, split * KS,
                P2 + (size_t)split * (HB * HD));
}

// Deterministic partial reduction + bias + activation for q/k/v/f/i.
__global__ __launch_bounds__(256) void reduce_qkvfi(
    const float* __restrict__ P,
    const float* __restrict__ bq, const float* __restrict__ bk,
    const float* __restrict__ bv, const float* __restrict__ bfv,
    const float* __restrict__ biv,
    float* __restrict__ q, float* __restrict__ k, float* __restrict__ v,
    float* __restrict__ fg, float* __restrict__ ig)
{
    const int o = blockIdx.x * 256 + threadIdx.x;   // 0..327679
    const int g = o >> 16;
    const int rem = o & 65535;
    const int m = rem & (HD - 1);
    int base, ns, act; const float* bias; float* out;
    switch (g) {
        case 0:  base = 0;  ns = 8;  bias = bq;  out = q;  act = 0; break;
        case 1:  base = 8;  ns = 8;  bias = bk;  out = k;  act = 0; break;
        case 2:  base = 16; ns = 8;  bias = bv;  out = v;  act = 0; break;
        case 3:  base = 24; ns = 16; bias = bfv; out = fg; act = 1; break;
        default: base = 40; ns = 16; bias = biv; out = ig; act = 1; break;
    }
    float s = bias[m];
    for (int i = 0; i < ns; ++i) s += P[(size_t)(base + i) * 65536 + rem];
    if (act) s = 1.0f / (1.0f + expf(-s));
    out[rem] = s;
}

__global__ __launch_bounds__(256) void reduce_out(
    const float* __restrict__ P2, const float* __restrict__ bo,
    float* __restrict__ hnew)
{
    const int o = blockIdx.x * 256 + threadIdx.x;   // 0..65535
    const int m = o & (HD - 1);
    float s = bo[m];
    #pragma unroll
    for (int i = 0; i < 8; ++i) s += P2[(size_t)i * 65536 + o];
    hnew[o] = s;
}

// ---------------------------------------------------------------------------
// Fused C update + readout (the HBM-roofline kernel, 512 MB of traffic):
//   Cn[b,m,n] = f[b,m]*C[b,m,n] + (i[b,m]*k[b,m])*v[b,n]
//   tr[b,m]   = tanh( sum_n Cn[b,m,n] * q[b,n] )
// One wave per (b,m) row; non-temporal on the C streams (no reuse).
// ---------------------------------------------------------------------------
__global__ __launch_bounds__(256) void update_kernel(
    const float* __restrict__ C,
    const float* __restrict__ q, const float* __restrict__ k,
    const float* __restrict__ v, const float* __restrict__ fg,
    const float* __restrict__ ig,
    float* __restrict__ Cn, float* __restrict__ tr)
{
    const int wid  = threadIdx.x >> 6;
    const int lane = threadIdx.x & 63;
    const int row  = blockIdx.x * 4 + wid;      // 0 .. B*HD-1
    const int b    = row >> 10;
    const int m    = row & (HD - 1);

    const float fm  = fg[b * HD + m];
    const float ikm = ig[b * HD + m] * k[b * HD + m];

    const f32x4* C4 = (const f32x4*)C;
    const float4* V4 = (const float4*)v;
    const float4* Q4 = (const float4*)q;
    f32x4*       N4 = (f32x4*)Cn;

    const int base  = row * (HD / 4);
    const int vbase = b * (HD / 4);

    float racc = 0.f;
    #pragma unroll
    for (int j = 0; j < 4; ++j) {
        int o = lane + 64 * j;
        f32x4 c4 = __builtin_nontemporal_load(&C4[base + o]);
        float4 v4 = V4[vbase + o];
        float4 q4 = Q4[vbase + o];
        f32x4 cn;
        cn.x = fmaf(fm, c4.x, ikm * v4.x);
        cn.y = fmaf(fm, c4.y, ikm * v4.y);
        cn.z = fmaf(fm, c4.z, ikm * v4.z);
        cn.w = fmaf(fm, c4.w, ikm * v4.w);
        __builtin_nontemporal_store(cn, &N4[base + o]);
        racc += cn.x * q4.x + cn.y * q4.y + cn.z * q4.z + cn.w * q4.w;
    }
    #pragma unroll
    for (int off = 32; off; off >>= 1) racc += __shfl_xor(racc, off);
    if (lane == 0) tr[row] = tanhf(racc);
}

extern "C" void kernel_launch(void* const* d_in, const int* in_sizes, int n_in,
                              void* d_out, int out_size, void* d_ws, size_t ws_size,
                              hipStream_t stream) {
    const float* x  = (const float*)d_in[0];
    const float* h  = (const float*)d_in[1];
    const float* C  = (const float*)d_in[2];
    const float* Wq = (const float*)d_in[3];
    const float* bq = (const float*)d_in[4];
    const float* Wk = (const float*)d_in[5];
    const float* bk = (const float*)d_in[6];
    const float* Wv = (const float*)d_in[7];
    const float* bv = (const float*)d_in[8];
    const float* Wf = (const float*)d_in[9];
    const float* bf = (const float*)d_in[10];
    const float* Wi = (const float*)d_in[11];
    const float* bi = (const float*)d_in[12];
    const float* Wo = (const float*)d_in[13];
    const float* bo = (const float*)d_in[14];

    float* outp = (float*)d_out;
    float* hnew = outp;                    // [B,HD]
    float* Cn   = outp + HB * HD;          // [B,HD,HD]

    const size_t SL = (size_t)HB * HD;     // 65536
    float* ws = (float*)d_ws;
    float* q  = ws + 0 * SL;
    float* k  = ws + 1 * SL;
    float* v  = ws + 2 * SL;
    float* fg = ws + 3 * SL;
    float* ig = ws + 4 * SL;
    float* tr = ws + 5 * SL;
    float* P  = ws + 6 * SL;               // 56 slabs
    float* P2 = ws + 62 * SL;              // 8 slabs

    qkvfi_splitk<<<dim3(16, 56), 256, 0, stream>>>(x, h, Wq, Wk, Wv, Wf, Wi, P);
    reduce_qkvfi<<<dim3(1280), 256, 0, stream>>>(P, bq, bk, bv, bf, bi,
                                                 q, k, v, fg, ig);
    update_kernel<<<dim3((HB * HD) / 4), 256, 0, stream>>>(
        C, q, k, v, fg, ig, Cn, tr);
    out_splitk<<<dim3(16, 8), 256, 0, stream>>>(tr, Wo, P2);
    reduce_out<<<dim3(256), 256, 0, stream>>>(P2, bo, hnew);
}